// Round 15
// baseline (108.288 us; speedup 1.0000x reference)
//
#include <hip/hip_runtime.h>
#include <math.h>

// Quantum circuit simulator: BATCH=2048 states x 1024 complex amplitudes,
// QDEPTH=8 layers of StronglyEntanglingLayers (10 Rot gates + 10 CNOTs).
//
// Round-15 = r13 t-packing (VALU halved, validated 48.6us) x r12 2-wave
// topology (tables/fold/barrier scheme absmax-validated). Stall model from
// r13/r14: wall 48.6 with VALU 46% and DS 41% -- latency-bound at 2
// waves/SIMD. This doubles waves/SIMD while keeping packed math.
//   i = (w<<9) | (lane<<3) | t,   tid = (w<<6) | lane,  8 amps/lane
//   packs: zr[k] = (re[t=k], re[t=k+4]), zi likewise, k=0..3
// Gates:
//  - wire 9 (t-bit0): cross-pack mask 1; wire 8 (t-bit1): cross-pack mask 2
//  - wire 7 (t-bit2 = pack dim): in-pack half-swap (r13 wire-6 pattern)
//  - wires 6,5,4,3 (lane bits 0..3): DPP row ops (VALU pipe)
//  - wires 2,1 (lane bits 4,5): __shfl_xor 16/32
//  - wire 0 (wave bit 9): folded into CNOT read (r12-validated math, packed):
//      new[i] = c0*psi[j] + c1*psi[j^512], j=g(i); word(j^512)=jw^64;
//      role bit = bit6(jw); per-half coeff selection packed into v2f.
// LDS: t-major b32 word(i) = t*128 + tid (bank = tid%32, conflict-free),
// double-buffered 16KB -> ONE barrier/layer (safety argument validated r12).
// DS insts/wave/layer = 80 (32 bpermute + 16 writes + 32 reads).

#define WIRES   10
#define NSTATE  1024
#define QDEPTH  8
#define NBATCH  2048
#define NGATES  (QDEPTH * WIRES)

typedef float v2f __attribute__((ext_vector_type(2)));
static __device__ __forceinline__ v2f s2(float x) { return (v2f){x, x}; }

// ws layout (4-B words)  [identical to r12 -- validated]:
//   [0   .. 640)   gate coeffs (l*10+q): u00r,u00i,u01r,u01i,u10r,u10i,u11r,u11i
//   [640 .. 704)   int gt8[l*8 + t]    = word(g_l(t)),  t in [0,8)
//   [704 .. 1728)  int gl[l*128 + tid] = word(g_l((tid>>6)<<9 | (tid&63)<<3))
#define WS_WORDS 1728

__device__ __forceinline__ int perm_g(int j, int r) {
#pragma unroll
    for (int q = WIRES - 1; q >= 0; --q) {
        const int cb = 9 - q;
        const int tb = 9 - ((q + r) % WIRES);
        j ^= ((j >> cb) & 1) << tb;
    }
    return j;
}
__device__ __forceinline__ int wordof(int j) {   // bit permutation (linear)
    return ((j & 7) << 7) | (j >> 3);            // = t*128 + tid
}

__global__ __launch_bounds__(1024) void qprep(
    const float* __restrict__ weights, float* __restrict__ ws)
{
    const int tid = threadIdx.x;
    if (tid < NGATES) {
        const float phi   = tanhf(weights[tid * 3 + 0]);
        const float theta = tanhf(weights[tid * 3 + 1]);
        const float omega = tanhf(weights[tid * 3 + 2]);
        const float c  = cosf(theta * 0.5f);
        const float sn = sinf(theta * 0.5f);
        const float a  = 0.5f * (phi + omega);
        const float bb = 0.5f * (phi - omega);
        const float ca = cosf(a),  sa = sinf(a);
        const float cb = cosf(bb), sb = sinf(bb);
        // U00 = e^{-ia} c ; U01 = -e^{+ib} s ; U10 = e^{-ib} s ; U11 = e^{+ia} c
        ws[tid * 8 + 0] =  ca * c;  ws[tid * 8 + 1] = -sa * c;
        ws[tid * 8 + 2] = -cb * sn; ws[tid * 8 + 3] = -sb * sn;
        ws[tid * 8 + 4] =  cb * sn; ws[tid * 8 + 5] = -sb * sn;
        ws[tid * 8 + 6] =  ca * c;  ws[tid * 8 + 7] =  sa * c;
    }
    int* wsI = (int*)ws;
    if (tid >= 128 && tid < 192) {          // gt8: 8 layers x 8 t values
        const int e = tid - 128, l = e >> 3, t = e & 7;
        wsI[640 + e] = wordof(perm_g(t, (l % (WIRES - 1)) + 1));
    }
    {                                       // gl: 8 layers x 128 thread bases
        const int l = tid >> 7, e = tid & 127;
        const int i0 = ((e >> 6) << 9) | ((e & 63) << 3);
        wsI[704 + tid] = wordof(perm_g(i0, (l % (WIRES - 1)) + 1));
    }
}

// DPP cross-lane move (VALU pipe, rows of 16 lanes) — validated r9/r13
template<int CTRL>
__device__ __forceinline__ float dppmov(float x) {
    return __int_as_float(__builtin_amdgcn_update_dpp(
        0, __float_as_int(x), CTRL, 0xF, 0xF, true));
}
#define FX1(v)  dppmov<0xB1>(v)
#define FX2(v)  dppmov<0x4E>(v)
#define FX4(v)  dppmov<0x1B>(dppmov<0x141>(v))
#define FX8(v)  dppmov<0x128>(v)
#define FX16(v) __shfl_xor((v), 16, 64)
#define FX32(v) __shfl_xor((v), 32, 64)

// cross-pack 2x2 gate along k-bit mask (1,2): packed element-wise math
#define APPLY_LOCAL_PK4(uptr, mask)                                           \
    {                                                                         \
        const float* __restrict__ u = (uptr);                                 \
        const float u00r=u[0], u00i=u[1], u01r=u[2], u01i=u[3];               \
        const float u10r=u[4], u10i=u[5], u11r=u[6], u11i=u[7];               \
        _Pragma("unroll")                                                     \
        for (int k0 = 0; k0 < 4; ++k0) {                                      \
            if (k0 & (mask)) continue;                                        \
            const int k1 = k0 | (mask);                                       \
            const v2f a0r = zr[k0], a0i = zi[k0];                             \
            const v2f a1r = zr[k1], a1i = zi[k1];                             \
            zr[k0] = s2(u00r)*a0r - s2(u00i)*a0i + s2(u01r)*a1r - s2(u01i)*a1i;\
            zi[k0] = s2(u00r)*a0i + s2(u00i)*a0r + s2(u01r)*a1i + s2(u01i)*a1r;\
            zr[k1] = s2(u10r)*a0r - s2(u10i)*a0i + s2(u11r)*a1r - s2(u11i)*a1i;\
            zi[k1] = s2(u10r)*a0i + s2(u10i)*a0r + s2(u11r)*a1i + s2(u11i)*a1r;\
        }                                                                     \
    }

// gate on lane-bit J (wire W): partner via per-half FETCH, scalar coeffs
#define LANE_GATE_PK4(W, J, FETCH)                                            \
    {                                                                         \
        const float* __restrict__ u = gw + (W) * 8;                           \
        const bool hi = (lane >> (J)) & 1;                                    \
        const float c0r = hi ? u[6] : u[0], c0i = hi ? u[7] : u[1];           \
        const float c1r = hi ? u[4] : u[2], c1i = hi ? u[5] : u[3];           \
        _Pragma("unroll")                                                     \
        for (int k = 0; k < 4; ++k) {                                         \
            v2f pr, pi;                                                       \
            pr.x = FETCH(zr[k].x); pr.y = FETCH(zr[k].y);                     \
            pi.x = FETCH(zi[k].x); pi.y = FETCH(zi[k].y);                     \
            const v2f sr = zr[k], si = zi[k];                                 \
            zr[k] = s2(c0r)*sr - s2(c0i)*si + s2(c1r)*pr - s2(c1i)*pi;        \
            zi[k] = s2(c0r)*si + s2(c0i)*sr + s2(c1r)*pi + s2(c1i)*pr;        \
        }                                                                     \
    }

__global__ __launch_bounds__(128) void qsim2p(
    const float* __restrict__ x,
    const float* __restrict__ ws,
    float* __restrict__ out,
    const int interleaved)
{
    __shared__ float lre[2][NSTATE];        // double-buffered: 1 barrier/layer
    __shared__ float lim[2][NSTATE];
    const int tid  = threadIdx.x;           // 0..127
    const int lane = tid & 63;
    const int b    = blockIdx.x;
    const int i0   = ((tid >> 6) << 9) | (lane << 3);   // base amp index
    const int* __restrict__ wsI = (const int*)ws;

    // packs over t: zr[k] = (re[t=k], re[t=k+4]), k=0..3
    v2f zr[4], zi[4];

    // ---- load 8 contiguous amplitudes (real input, imag = 0) ----
    const float4* __restrict__ x4 =
        (const float4*)(x + ((size_t)b << 10) + i0);
    {
        const float4 v0 = x4[0], v1 = x4[1];   // t=0..3, t=4..7
        zr[0] = (v2f){v0.x, v1.x};
        zr[1] = (v2f){v0.y, v1.y};
        zr[2] = (v2f){v0.z, v1.z};
        zr[3] = (v2f){v0.w, v1.w};
#pragma unroll
        for (int k = 0; k < 4; ++k) zi[k] = (v2f){0.f, 0.f};
    }

    for (int l = 0; l < QDEPTH; ++l) {
        const float* __restrict__ gw = ws + l * 80;
        float* __restrict__ bre = lre[l & 1];
        float* __restrict__ bim = lim[l & 1];

        // ---- t-bit gates: wire 9 (mask 1), wire 8 (mask 2) cross-pack ----
        APPLY_LOCAL_PK4(gw + 9*8, 1)
        APPLY_LOCAL_PK4(gw + 8*8, 2)

        // ---- wire 7 = t-bit 2 = pack dim: lo<->hi half-swap ----
        {
            const float* __restrict__ u = gw + 7*8;
            const v2f pAr = (v2f){u[0], u[6]};   // (u00r, u11r)
            const v2f pAi = (v2f){u[1], u[7]};   // (u00i, u11i)
            const v2f pBr = (v2f){u[2], u[4]};   // (u01r, u10r)
            const v2f pBi = (v2f){u[3], u[5]};   // (u01i, u10i)
#pragma unroll
            for (int k = 0; k < 4; ++k) {
                const v2f r  = zr[k], i = zi[k];
                const v2f rs = __builtin_shufflevector(r, r, 1, 0);
                const v2f is = __builtin_shufflevector(i, i, 1, 0);
                zr[k] = pAr*r - pAi*i + pBr*rs - pBi*is;
                zi[k] = pAr*i + pAi*r + pBr*is + pBi*rs;
            }
        }

        // ---- lane-bit gates: wires 6..3 on DPP, wires 2,1 via shfl ----
        LANE_GATE_PK4(6, 0, FX1)
        LANE_GATE_PK4(5, 1, FX2)
        LANE_GATE_PK4(4, 2, FX4)
        LANE_GATE_PK4(3, 3, FX8)
        LANE_GATE_PK4(2, 4, FX16)
        LANE_GATE_PK4(1, 5, FX32)

        // ---- stage to LDS, t-major b32: word(i) = t*128 + tid ----
#pragma unroll
        for (int k = 0; k < 4; ++k) {
            bre[k * 128 + tid]       = zr[k].x;
            bre[(k + 4) * 128 + tid] = zr[k].y;
            bim[k * 128 + tid]       = zi[k].x;
            bim[(k + 4) * 128 + tid] = zi[k].y;
        }
        __syncthreads();

        // ---- wire-0 gate folded into CNOT permutation read (r12 math) ----
        // new[i] = c0*psi[j] + c1*psi[j^512]; word(j^512)=jw^64; role=bit6(jw)
        const float* __restrict__ u0 = gw;          // wire 0 coeffs
        const int glw = wsI[704 + l * 128 + tid];   // word(g(i0))
#pragma unroll
        for (int k = 0; k < 4; ++k) {
            const int jw0 = glw ^ wsI[640 + l * 8 + k];
            const int jw1 = glw ^ wsI[640 + l * 8 + k + 4];
            const bool h0 = (jw0 >> 6) & 1, h1 = (jw1 >> 6) & 1;
            const v2f c0r = (v2f){h0 ? u0[6] : u0[0], h1 ? u0[6] : u0[0]};
            const v2f c0i = (v2f){h0 ? u0[7] : u0[1], h1 ? u0[7] : u0[1]};
            const v2f c1r = (v2f){h0 ? u0[4] : u0[2], h1 ? u0[4] : u0[2]};
            const v2f c1i = (v2f){h0 ? u0[5] : u0[3], h1 ? u0[5] : u0[3]};
            const v2f sr = (v2f){bre[jw0],      bre[jw1]};
            const v2f si = (v2f){bim[jw0],      bim[jw1]};
            const v2f pr = (v2f){bre[jw0 ^ 64], bre[jw1 ^ 64]};
            const v2f pi = (v2f){bim[jw0 ^ 64], bim[jw1 ^ 64]};
            zr[k] = c0r*sr - c0i*si + c1r*pr - c1i*pi;
            zi[k] = c0r*si + c0i*sr + c1r*pi + c1i*pr;
        }
        // no second barrier: double-buffered; a buffer is re-written only two
        // layers later, after an intervening barrier (scheme validated r12)
    }

    // ---- epilogue ----
    if (interleaved) {
        float2* __restrict__ o2 = (float2*)out;
        const size_t base = ((size_t)b << 10) + i0;
#pragma unroll
        for (int k = 0; k < 4; ++k) {
            o2[base + k]     = make_float2(zr[k].x, zi[k].x);
            o2[base + k + 4] = make_float2(zr[k].y, zi[k].y);
        }
    } else {
        // harness compares real part only (complex64 expected cast to f32)
        float4* __restrict__ o4 = (float4*)(out + ((size_t)b << 10) + i0);
        o4[0] = make_float4(zr[0].x, zr[1].x, zr[2].x, zr[3].x);
        o4[1] = make_float4(zr[0].y, zr[1].y, zr[2].y, zr[3].y);
    }
}

// ---------------- validated round-6 fallback (ws too small) ----------------
__global__ __launch_bounds__(256) void qcircuit_kernel(
    const float* __restrict__ x, const float* __restrict__ weights,
    float* __restrict__ out, const int interleaved)
{
    __shared__ float s_re[NSTATE];
    __shared__ float s_im[NSTATE];
    __shared__ float s_g[NGATES][8];
    const int tid = threadIdx.x;
    const int b   = blockIdx.x;
    if (tid < NGATES) {
        const float phi   = tanhf(weights[tid * 3 + 0]);
        const float theta = tanhf(weights[tid * 3 + 1]);
        const float omega = tanhf(weights[tid * 3 + 2]);
        const float c  = cosf(theta * 0.5f);
        const float sn = sinf(theta * 0.5f);
        const float a  = 0.5f * (phi + omega);
        const float bb = 0.5f * (phi - omega);
        const float ca = cosf(a),  sa = sinf(a);
        const float cb = cosf(bb), sb = sinf(bb);
        s_g[tid][0] =  ca * c;  s_g[tid][1] = -sa * c;
        s_g[tid][2] = -cb * sn; s_g[tid][3] = -sb * sn;
        s_g[tid][4] =  cb * sn; s_g[tid][5] = -sb * sn;
        s_g[tid][6] =  ca * c;  s_g[tid][7] =  sa * c;
    }
#pragma unroll
    for (int k = 0; k < 4; ++k) {
        const int i = tid + 256 * k;
        s_re[i] = x[b * NSTATE + i];
        s_im[i] = 0.0f;
    }
    __syncthreads();
    for (int l = 0; l < QDEPTH; ++l) {
        for (int q = 0; q < WIRES; ++q) {
            const int gi = l * WIRES + q;
            const float u00r = s_g[gi][0], u00i = s_g[gi][1];
            const float u01r = s_g[gi][2], u01i = s_g[gi][3];
            const float u10r = s_g[gi][4], u10i = s_g[gi][5];
            const float u11r = s_g[gi][6], u11i = s_g[gi][7];
            const int sh = 9 - q;
            const int m  = 1 << sh;
#pragma unroll
            for (int k = 0; k < 2; ++k) {
                const int p  = tid + 256 * k;
                const int i0 = ((p >> sh) << (sh + 1)) | (p & (m - 1));
                const int i1 = i0 | m;
                const float a0r = s_re[i0], a0i = s_im[i0];
                const float a1r = s_re[i1], a1i = s_im[i1];
                s_re[i0] = u00r*a0r - u00i*a0i + u01r*a1r - u01i*a1i;
                s_im[i0] = u00r*a0i + u00i*a0r + u01r*a1i + u01i*a1r;
                s_re[i1] = u10r*a0r - u10i*a0i + u11r*a1r - u11i*a1i;
                s_im[i1] = u10r*a0i + u10i*a0r + u11r*a1i + u11i*a1r;
            }
            __syncthreads();
        }
        const int r = (l % (WIRES - 1)) + 1;
        float vr[4], vi[4];
#pragma unroll
        for (int k = 0; k < 4; ++k) {
            const int i = tid + 256 * k;
            const int j = perm_g(i, r);
            vr[k] = s_re[j]; vi[k] = s_im[j];
        }
        __syncthreads();
#pragma unroll
        for (int k = 0; k < 4; ++k) {
            const int i = tid + 256 * k;
            s_re[i] = vr[k]; s_im[i] = vi[k];
        }
        __syncthreads();
    }
    if (interleaved) {
#pragma unroll
        for (int k = 0; k < 4; ++k) {
            const int i  = tid + 256 * k;
            const int fi = 2 * (b * NSTATE + i);
            out[fi + 0] = s_re[i];
            out[fi + 1] = s_im[i];
        }
    } else {
#pragma unroll
        for (int k = 0; k < 4; ++k) {
            const int i = tid + 256 * k;
            out[b * NSTATE + i] = s_re[i];
        }
    }
}

extern "C" void kernel_launch(void* const* d_in, const int* in_sizes, int n_in,
                              void* d_out, int out_size, void* d_ws, size_t ws_size,
                              hipStream_t stream) {
    const float* x       = (const float*)d_in[0];   // (2048,1,32,32) f32
    const float* weights = (const float*)d_in[1];   // (8,10,3) f32
    float* out = (float*)d_out;
    const int interleaved = (out_size >= 2 * NBATCH * NSTATE) ? 1 : 0;

    if (ws_size >= WS_WORDS * sizeof(float)) {
        float* ws = (float*)d_ws;
        qprep<<<1, 1024, 0, stream>>>(weights, ws);
        qsim2p<<<NBATCH, 128, 0, stream>>>(x, ws, out, interleaved);
    } else {
        qcircuit_kernel<<<NBATCH, 256, 0, stream>>>(x, weights, out, interleaved);
    }
}

// Round 16
// 104.104 us; speedup vs baseline: 1.0402x; 1.0402x over previous
//
#include <hip/hip_runtime.h>
#include <math.h>

// Quantum circuit simulator: BATCH=2048 states x 1024 complex amplitudes,
// QDEPTH=8 layers of StronglyEntanglingLayers (10 Rot gates + 10 CNOTs).
//
// FINAL (= round-13, validated best: kernel 48.6us, harness 103.7us).
// Session map (kernel-only times):
//   r6 LDS/256thr 96us -> r7 wave/state+shfl 66us -> r9 +DPP 53.5us
//   -> r13 +t-dim packing (v_pk_fma) 48.6us   [this kernel]
// Closed axes (measured, explained):
//   - state split across waves (r10/r12/r15): +VALU time 50-100% each try;
//     total waves capped at 2048 => occupancy locked at 2 waves/SIMD.
//   - (re,im) packing (r11): J-swizzle cost == pk gain.
//   - b64/b128/paired LDS (r8/r10/r14): bank-structure losses; only
//     t-major b32 word(i)=(i&15)*64+(i>>4) is conflict-free (1.3e5).
// Structure: one wave per state, 16 complex amps/lane, packed over t:
//   zr[k]=(re[t=k],re[t=k+8]), zi likewise -> element-wise v_pk_fma_f32
//   with wave-uniform scalar coeffs (VALU busy 38us -> 22.6us).
//  - wires 9..7 (t-bits 0..2): cross-pack register gates.
//  - wire 6 (t-bit 3 = pack dim): in-pack half-swap, packed constants.
//  - wires 5..2 (lane xor 1,2,4,8): DPP row ops (VALU pipe).
//  - wires 1,0 (lane xor 16,32): __shfl_xor.
//  - CNOT stage: composed GF(2)-linear permutation (g), one LDS round trip,
//    XOR-decomposed address tables in d_ws. No __syncthreads (single wave).

#define WIRES   10
#define NSTATE  1024
#define QDEPTH  8
#define NBATCH  2048
#define NGATES  (QDEPTH * WIRES)

typedef float v2f __attribute__((ext_vector_type(2)));
static __device__ __forceinline__ v2f s2(float x) { return (v2f){x, x}; }

// ws layout (floats/ints, 4 B each):
//   [0   .. 640)  gate coeffs gi=(l*10+q): u00r,u00i,u01r,u01i,u10r,u10i,u11r,u11i
//   [640 .. 768)  int gt[l*16+t]    = word(g_l(t))
//   [768 .. 1280) int glane[l*64+v] = word(g_l(v<<4))
#define WS_WORDS 1280

__device__ __forceinline__ int perm_g(int j, int r) {
#pragma unroll
    for (int q = WIRES - 1; q >= 0; --q) {
        const int cb = 9 - q;
        const int tb = 9 - ((q + r) % WIRES);
        j ^= ((j >> cb) & 1) << tb;
    }
    return j;
}

__global__ __launch_bounds__(1024) void qprep(
    const float* __restrict__ weights, float* __restrict__ ws)
{
    const int tid = threadIdx.x;
    if (tid < NGATES) {
        const float phi   = tanhf(weights[tid * 3 + 0]);
        const float theta = tanhf(weights[tid * 3 + 1]);
        const float omega = tanhf(weights[tid * 3 + 2]);
        const float c  = cosf(theta * 0.5f);
        const float sn = sinf(theta * 0.5f);
        const float a  = 0.5f * (phi + omega);
        const float bb = 0.5f * (phi - omega);
        const float ca = cosf(a),  sa = sinf(a);
        const float cb = cosf(bb), sb = sinf(bb);
        // U00 = e^{-ia} c ; U01 = -e^{+ib} s ; U10 = e^{-ib} s ; U11 = e^{+ia} c
        ws[tid * 8 + 0] =  ca * c;  ws[tid * 8 + 1] = -sa * c;
        ws[tid * 8 + 2] = -cb * sn; ws[tid * 8 + 3] = -sb * sn;
        ws[tid * 8 + 4] =  cb * sn; ws[tid * 8 + 5] = -sb * sn;
        ws[tid * 8 + 6] =  ca * c;  ws[tid * 8 + 7] =  sa * c;
    }
    int* wsI = (int*)ws;
    if (tid >= 128 && tid < 256) {          // gt table: 8 layers x 16 t
        const int e = tid - 128, l = e >> 4, t = e & 15;
        const int j = perm_g(t, (l % (WIRES - 1)) + 1);
        wsI[640 + e] = ((j & 15) << 6) | (j >> 4);
    }
    if (tid >= 256 && tid < 768) {          // glane table: 8 layers x 64 lanes
        const int e = tid - 256, l = e >> 6, v = e & 63;
        const int j = perm_g(v << 4, (l % (WIRES - 1)) + 1);
        wsI[768 + e] = ((j & 15) << 6) | (j >> 4);
    }
}

// DPP cross-lane move (VALU pipe, rows of 16 lanes) — validated r9/r13
template<int CTRL>
__device__ __forceinline__ float dppmov(float x) {
    return __int_as_float(__builtin_amdgcn_update_dpp(
        0, __float_as_int(x), CTRL, 0xF, 0xF, true));
}
#define FX1(v)  dppmov<0xB1>(v)
#define FX2(v)  dppmov<0x4E>(v)
#define FX4(v)  dppmov<0x1B>(dppmov<0x141>(v))
#define FX8(v)  dppmov<0x128>(v)
#define FX16(v) __shfl_xor((v), 16, 64)
#define FX32(v) __shfl_xor((v), 32, 64)

// local 2x2 gate along t-bit mask (1,2,4): partner in a DIFFERENT pack,
// matching halves -> pure packed element-wise math, scalar coeffs
#define APPLY_LOCAL_PK(uptr, mask)                                            \
    {                                                                         \
        const float* __restrict__ u = (uptr);                                 \
        const float u00r=u[0], u00i=u[1], u01r=u[2], u01i=u[3];               \
        const float u10r=u[4], u10i=u[5], u11r=u[6], u11i=u[7];               \
        _Pragma("unroll")                                                     \
        for (int k0 = 0; k0 < 8; ++k0) {                                      \
            if (k0 & (mask)) continue;                                        \
            const int k1 = k0 | (mask);                                       \
            const v2f a0r = zr[k0], a0i = zi[k0];                             \
            const v2f a1r = zr[k1], a1i = zi[k1];                             \
            zr[k0] = s2(u00r)*a0r - s2(u00i)*a0i + s2(u01r)*a1r - s2(u01i)*a1i;\
            zi[k0] = s2(u00r)*a0i + s2(u00i)*a0r + s2(u01r)*a1i + s2(u01i)*a1r;\
            zr[k1] = s2(u10r)*a0r - s2(u10i)*a0i + s2(u11r)*a1r - s2(u11i)*a1i;\
            zi[k1] = s2(u10r)*a0i + s2(u10i)*a0r + s2(u11r)*a1i + s2(u11i)*a1r;\
        }                                                                     \
    }

// gate on lane-bit J (wire W): partner via per-half FETCH, scalar coeffs
#define LANE_GATE_PK(W, J, FETCH)                                             \
    {                                                                         \
        const float* __restrict__ u = gw + (W) * 8;                           \
        const bool hi = (lane >> (J)) & 1;                                    \
        const float c0r = hi ? u[6] : u[0], c0i = hi ? u[7] : u[1];           \
        const float c1r = hi ? u[4] : u[2], c1i = hi ? u[5] : u[3];           \
        _Pragma("unroll")                                                     \
        for (int k = 0; k < 8; ++k) {                                         \
            v2f pr, pi;                                                       \
            pr.x = FETCH(zr[k].x); pr.y = FETCH(zr[k].y);                     \
            pi.x = FETCH(zi[k].x); pi.y = FETCH(zi[k].y);                     \
            const v2f sr = zr[k], si = zi[k];                                 \
            zr[k] = s2(c0r)*sr - s2(c0i)*si + s2(c1r)*pr - s2(c1i)*pi;        \
            zi[k] = s2(c0r)*si + s2(c0i)*sr + s2(c1r)*pi + s2(c1i)*pr;        \
        }                                                                     \
    }

__global__ __launch_bounds__(64) void qsim_wave(
    const float* __restrict__ x,
    const float* __restrict__ ws,
    float* __restrict__ out,
    const int interleaved)
{
    __shared__ float lre[NSTATE];
    __shared__ float lim[NSTATE];
    const int lane = threadIdx.x;           // 0..63
    const int b    = blockIdx.x;
    const int* __restrict__ wsI = (const int*)ws;

    // packed planes: zr[k] = (re[t=k], re[t=k+8]); zi likewise
    v2f zr[8], zi[8];

    // ---- load 16 contiguous amplitudes (real input, imag = 0) ----
    const float4* __restrict__ x4 =
        (const float4*)(x + ((size_t)b << 10) + (lane << 4));
    {
        const float4 v0 = x4[0], v1 = x4[1], v2 = x4[2], v3 = x4[3];
        zr[0].x=v0.x; zr[1].x=v0.y; zr[2].x=v0.z; zr[3].x=v0.w;
        zr[4].x=v1.x; zr[5].x=v1.y; zr[6].x=v1.z; zr[7].x=v1.w;
        zr[0].y=v2.x; zr[1].y=v2.y; zr[2].y=v2.z; zr[3].y=v2.w;
        zr[4].y=v3.x; zr[5].y=v3.y; zr[6].y=v3.z; zr[7].y=v3.w;
#pragma unroll
        for (int k = 0; k < 8; ++k) zi[k] = (v2f){0.f, 0.f};
    }

    for (int l = 0; l < QDEPTH; ++l) {
        const float* __restrict__ gw = ws + l * 80;

        // ---- local gates: t-bits 0,1,2 = wires 9,8,7 (cross-pack) ----
        APPLY_LOCAL_PK(gw + 9*8, 1)
        APPLY_LOCAL_PK(gw + 8*8, 2)
        APPLY_LOCAL_PK(gw + 7*8, 4)

        // ---- t-bit 3 = wire 6: lo<->hi within each pack (half-swap) ----
        {
            const float* __restrict__ u = gw + 6*8;
            const v2f pAr = (v2f){u[0], u[6]};   // (u00r, u11r)
            const v2f pAi = (v2f){u[1], u[7]};   // (u00i, u11i)
            const v2f pBr = (v2f){u[2], u[4]};   // (u01r, u10r)
            const v2f pBi = (v2f){u[3], u[5]};   // (u01i, u10i)
#pragma unroll
            for (int k = 0; k < 8; ++k) {
                const v2f r  = zr[k], i = zi[k];
                const v2f rs = __builtin_shufflevector(r, r, 1, 0);
                const v2f is = __builtin_shufflevector(i, i, 1, 0);
                zr[k] = pAr*r - pAi*i + pBr*rs - pBi*is;
                zi[k] = pAr*i + pAi*r + pBr*is + pBi*rs;
            }
        }

        // ---- lane-bit gates: wires 5..2 on DPP, wires 1,0 via shfl ----
        LANE_GATE_PK(5, 0, FX1)
        LANE_GATE_PK(4, 1, FX2)
        LANE_GATE_PK(3, 2, FX4)
        LANE_GATE_PK(2, 3, FX8)
        LANE_GATE_PK(1, 4, FX16)
        LANE_GATE_PK(0, 5, FX32)

        // ---- CNOT stage: new[i] = old[g(i)] via one LDS round trip ----
        // t-major b32 SoA, word(i) = t*64 + lane (bank = lane mod 32: free)
#pragma unroll
        for (int k = 0; k < 8; ++k) {
            lre[k * 64 + lane]         = zr[k].x;
            lre[(k + 8) * 64 + lane]   = zr[k].y;
            lim[k * 64 + lane]         = zi[k].x;
            lim[(k + 8) * 64 + lane]   = zi[k].y;
        }
        // single wave: per-wave DS ops execute in order; no barrier needed
        const int ga = wsI[768 + l * 64 + lane];    // word(g(lane<<4))
#pragma unroll
        for (int k = 0; k < 8; ++k) {
            const int a0 = ga ^ wsI[640 + l * 16 + k];
            const int a1 = ga ^ wsI[640 + l * 16 + k + 8];
            zr[k].x = lre[a0]; zi[k].x = lim[a0];
            zr[k].y = lre[a1]; zi[k].y = lim[a1];
        }
    }

    // ---- epilogue ----
    if (interleaved) {
        float2* __restrict__ o2 = (float2*)out;
        const size_t base = ((size_t)b << 10) + (lane << 4);
#pragma unroll
        for (int k = 0; k < 8; ++k) {
            o2[base + k]     = make_float2(zr[k].x, zi[k].x);
            o2[base + k + 8] = make_float2(zr[k].y, zi[k].y);
        }
    } else {
        // harness compares real part only (complex64 expected cast to float32)
        float4* __restrict__ o4 = (float4*)(out + ((size_t)b << 10) + (lane << 4));
        o4[0] = make_float4(zr[0].x, zr[1].x, zr[2].x, zr[3].x);
        o4[1] = make_float4(zr[4].x, zr[5].x, zr[6].x, zr[7].x);
        o4[2] = make_float4(zr[0].y, zr[1].y, zr[2].y, zr[3].y);
        o4[3] = make_float4(zr[4].y, zr[5].y, zr[6].y, zr[7].y);
    }
}

// ---------------- validated round-6 fallback (ws too small) ----------------
__global__ __launch_bounds__(256) void qcircuit_kernel(
    const float* __restrict__ x, const float* __restrict__ weights,
    float* __restrict__ out, const int interleaved)
{
    __shared__ float s_re[NSTATE];
    __shared__ float s_im[NSTATE];
    __shared__ float s_g[NGATES][8];
    const int tid = threadIdx.x;
    const int b   = blockIdx.x;
    if (tid < NGATES) {
        const float phi   = tanhf(weights[tid * 3 + 0]);
        const float theta = tanhf(weights[tid * 3 + 1]);
        const float omega = tanhf(weights[tid * 3 + 2]);
        const float c  = cosf(theta * 0.5f);
        const float sn = sinf(theta * 0.5f);
        const float a  = 0.5f * (phi + omega);
        const float bb = 0.5f * (phi - omega);
        const float ca = cosf(a),  sa = sinf(a);
        const float cb = cosf(bb), sb = sinf(bb);
        s_g[tid][0] =  ca * c;  s_g[tid][1] = -sa * c;
        s_g[tid][2] = -cb * sn; s_g[tid][3] = -sb * sn;
        s_g[tid][4] =  cb * sn; s_g[tid][5] = -sb * sn;
        s_g[tid][6] =  ca * c;  s_g[tid][7] =  sa * c;
    }
#pragma unroll
    for (int k = 0; k < 4; ++k) {
        const int i = tid + 256 * k;
        s_re[i] = x[b * NSTATE + i];
        s_im[i] = 0.0f;
    }
    __syncthreads();
    for (int l = 0; l < QDEPTH; ++l) {
        for (int q = 0; q < WIRES; ++q) {
            const int gi = l * WIRES + q;
            const float u00r = s_g[gi][0], u00i = s_g[gi][1];
            const float u01r = s_g[gi][2], u01i = s_g[gi][3];
            const float u10r = s_g[gi][4], u10i = s_g[gi][5];
            const float u11r = s_g[gi][6], u11i = s_g[gi][7];
            const int sh = 9 - q;
            const int m  = 1 << sh;
#pragma unroll
            for (int k = 0; k < 2; ++k) {
                const int p  = tid + 256 * k;
                const int i0 = ((p >> sh) << (sh + 1)) | (p & (m - 1));
                const int i1 = i0 | m;
                const float a0r = s_re[i0], a0i = s_im[i0];
                const float a1r = s_re[i1], a1i = s_im[i1];
                s_re[i0] = u00r*a0r - u00i*a0i + u01r*a1r - u01i*a1i;
                s_im[i0] = u00r*a0i + u00i*a0r + u01r*a1i + u01i*a1r;
                s_re[i1] = u10r*a0r - u10i*a0i + u11r*a1r - u11i*a1i;
                s_im[i1] = u10r*a0i + u10i*a0r + u11r*a1i + u11i*a1r;
            }
            __syncthreads();
        }
        const int r = (l % (WIRES - 1)) + 1;
        float vr[4], vi[4];
#pragma unroll
        for (int k = 0; k < 4; ++k) {
            const int i = tid + 256 * k;
            const int j = perm_g(i, r);
            vr[k] = s_re[j]; vi[k] = s_im[j];
        }
        __syncthreads();
#pragma unroll
        for (int k = 0; k < 4; ++k) {
            const int i = tid + 256 * k;
            s_re[i] = vr[k]; s_im[i] = vi[k];
        }
        __syncthreads();
    }
    if (interleaved) {
#pragma unroll
        for (int k = 0; k < 4; ++k) {
            const int i  = tid + 256 * k;
            const int fi = 2 * (b * NSTATE + i);
            out[fi + 0] = s_re[i];
            out[fi + 1] = s_im[i];
        }
    } else {
#pragma unroll
        for (int k = 0; k < 4; ++k) {
            const int i = tid + 256 * k;
            out[b * NSTATE + i] = s_re[i];
        }
    }
}

extern "C" void kernel_launch(void* const* d_in, const int* in_sizes, int n_in,
                              void* d_out, int out_size, void* d_ws, size_t ws_size,
                              hipStream_t stream) {
    const float* x       = (const float*)d_in[0];   // (2048,1,32,32) f32
    const float* weights = (const float*)d_in[1];   // (8,10,3) f32
    float* out = (float*)d_out;
    const int interleaved = (out_size >= 2 * NBATCH * NSTATE) ? 1 : 0;

    if (ws_size >= WS_WORDS * sizeof(float)) {
        float* ws = (float*)d_ws;
        qprep<<<1, 1024, 0, stream>>>(weights, ws);
        qsim_wave<<<NBATCH, 64, 0, stream>>>(x, ws, out, interleaved);
    } else {
        qcircuit_kernel<<<NBATCH, 256, 0, stream>>>(x, weights, out, interleaved);
    }
}